// Round 9
// baseline (198.750 us; speedup 1.0000x reference)
//
#include <hip/hip_runtime.h>

typedef unsigned short u16;
typedef __attribute__((ext_vector_type(8))) unsigned short u16x8;
typedef __attribute__((ext_vector_type(8))) __bf16 bf16x8;
typedef __attribute__((ext_vector_type(4))) float f32x4;

__device__ __forceinline__ float bf2f(u16 u) {
    return __uint_as_float(((unsigned)u) << 16);
}
__device__ __forceinline__ u16 f2bf(float f) {
    unsigned u = __float_as_uint(f);
    return (u16)((u + 0x7FFFu + ((u >> 16) & 1u)) >> 16);
}

// ---------------------------------------------------------------------------
// setup kernel: weight transform + pad zeroing + pre=relu(BN1(x)) transpose.
//   [0,3585): weights; [3585,5641): pre pad; [5641,9801): h1 pad;
//   [9801,11849): pre BN+ReLU NCHW f32 -> padded NHWC bf16 (interior)
// pre-transpose: coalesced 512B row-group reads (32 lanes x float4, one
// channel per group) + XOR-swizzled tile columns  col = c ^ ((x>>2 & 15)<<3)
// -> LDS write conflicts 16-way -> 4-way; read side stays contiguous u16x8
// (swizzle bits 3-6 don't overlap the k=0..7 channel bits).
// ---------------------------------------------------------------------------
__global__ __launch_bounds__(256)
void setup_kernel(const float* __restrict__ x,
                  const float* __restrict__ g1, const float* __restrict__ b1,
                  const float* __restrict__ m1, const float* __restrict__ v1,
                  const float* __restrict__ w1, const float* __restrict__ w2,
                  const float* __restrict__ wr,
                  const float* __restrict__ g2, const float* __restrict__ b2,
                  const float* __restrict__ m2, const float* __restrict__ v2,
                  u16* __restrict__ w1t, u16* __restrict__ w2t,
                  u16* __restrict__ wrt, float* __restrict__ bias2f,
                  u16* __restrict__ pre, u16* __restrict__ h1) {
    __shared__ u16 tile[128 * 136];
    __shared__ float scf[128], bif[128];
    int b = blockIdx.x;
    if (b < 3585) {
        int i = b * 256 + threadIdx.x;
        if (i < 294912) {
            int ci = i & 127; int t = i >> 7; int o = t & 255; int tap = t >> 8;
            int dy = tap / 3, dx = tap - dy * 3;
            float sc = g2[o] * rsqrtf(v2[o] + 1e-5f);
            w1t[i] = f2bf(w1[((o * 128 + ci) * 3 + dy) * 3 + dx] * sc);
        } else if (i < 294912 + 589824) {
            int j = i - 294912;
            int ci = j & 255; int t = j >> 8; int o = t & 255; int tap = t >> 8;
            int dy = tap / 3, dx = tap - dy * 3;
            w2t[j] = f2bf(w2[((o * 256 + ci) * 3 + dy) * 3 + dx]);
        } else if (i < 294912 + 589824 + 32768) {
            int j = i - (294912 + 589824);
            int ci = j & 127; int o = j >> 7;
            wrt[j] = f2bf(wr[o * 128 + ci]);
        } else {
            int o = i - (294912 + 589824 + 32768);
            if (o < 256) {
                float sc = g2[o] * rsqrtf(v2[o] + 1e-5f);
                bias2f[o] = b2[o] - m2[o] * sc;
            }
        }
    } else if (b < 3585 + 2056) {
        int i = (b - 3585) * 256 + threadIdx.x;
        if (i < 16 * 129 * 128) {
            int c = i & 127; int t = i >> 7; int n = t / 129; int xx = t - n * 129;
            pre[((n * 129 + 128) * 129 + xx) * 128 + c] = 0;
        } else {
            int j = i - 16 * 129 * 128;
            int c = j & 127; int t = j >> 7; int n = t >> 7; int y = t & 127;
            pre[((n * 129 + y) * 129 + 128) * 128 + c] = 0;
        }
    } else if (b < 3585 + 2056 + 4160) {
        int i = (b - (3585 + 2056)) * 256 + threadIdx.x;
        int c = i & 255;
        int t = i >> 8;
        int n = t / 260;
        int cl = t - n * 260;
        int y, x2;
        if (cl < 66)       { y = 0;  x2 = cl; }
        else if (cl < 132) { y = 65; x2 = cl - 66; }
        else if (cl < 196) { x2 = 0; y = cl - 131; }
        else               { x2 = 65; y = cl - 195; }
        h1[((n * 66 + y) * 66 + x2) * 256 + c] = 0;
    } else {
        int pb = b - (3585 + 2056 + 4160);
        int n = pb >> 7, y = pb & 127;
        int tid = threadIdx.x;
        if (tid < 128) {
            float sc = g1[tid] * rsqrtf(v1[tid] + 1e-5f);
            scf[tid] = sc;
            bif[tid] = b1[tid] - m1[tid] * sc;
        }
        __syncthreads();
        // read phase: 32-lane group reads one (c,y) row cooperatively.
        const int xq = (tid & 31) << 2;        // x base (4 consecutive x)
        const int cg = tid >> 5;               // channel sub-index 0..7
        const int sw = (tid & 15) << 3;        // swizzle = ((x>>2)&15)<<3
        const float* xb = x + (n << 21) + (y << 7) + xq;
#pragma unroll
        for (int i = 0; i < 16; ++i) {
            int c = i * 8 + cg;
            float4 val = *(const float4*)(xb + (c << 14));
            float sc = scf[c], bi = bif[c];
            int col = c ^ sw;
            tile[(xq + 0) * 136 + col] = f2bf(fmaxf(val.x * sc + bi, 0.f));
            tile[(xq + 1) * 136 + col] = f2bf(fmaxf(val.y * sc + bi, 0.f));
            tile[(xq + 2) * 136 + col] = f2bf(fmaxf(val.z * sc + bi, 0.f));
            tile[(xq + 3) * 136 + col] = f2bf(fmaxf(val.w * sc + bi, 0.f));
        }
        __syncthreads();
        // write phase: contiguous u16x8 (channels in order; swizzle bits 3-6
        // don't overlap k bits 0-2), coalesced NHWC stores
        int c0 = (tid & 15) << 3;
#pragma unroll
        for (int xi = 0; xi < 8; ++xi) {
            int xx = xi * 16 + (tid >> 4);
            int colb = c0 ^ (((xx >> 2) & 15) << 3);
            u16x8 val = *(const u16x8*)&tile[xx * 136 + colb];
            *(u16x8*)(pre + ((n * 129 + y) * 129 + xx) * 128 + c0) = val;
        }
    }
}

// ===========================================================================
// 256x256 implicit-GEMM conv.  A triple-buffered, B double-buffered.
// Deferred-quadrant software pipeline; one barrier + one counted vmcnt/tile.
// T1 XCD swizzle; T2 LDS swizzle via inverse-swizzled global source.
// POOL: conv2 fuses the SE global-avg partial sums into the epilogue.
// ===========================================================================
template <int CIN, int NTAPS, int STRIDE, bool BIASRELU, bool POOL>
__global__ __launch_bounds__(512, 2)
void conv_8ph(const u16* __restrict__ in, const u16* __restrict__ wt,
              const float* __restrict__ bias, u16* __restrict__ out,
              float* __restrict__ pool_out,
              int in_row, int in_img, int out_base, int out_row, int out_img) {
    constexpr int CSTEPS = CIN / 64;
    constexpr int KT = CSTEPS * NTAPS;
    // A buffers: 0, 16384, 32768 ; B buffers: 49152, 65536   (u16 units)
    __shared__ __attribute__((aligned(16))) u16 lds[81920];

    const int tid = threadIdx.x;
    const int w = tid >> 6, l = tid & 63;
    const int wm = w >> 2, wn = w & 3;
    const int l15 = l & 15;
    // T1: XCD-aware swizzle (bijective, 256 % 8 == 0)
    const int bid = ((blockIdx.x & 7) << 5) | (blockIdx.x >> 3);
    const int Mbase = bid << 8;

    const int srow = tid >> 3;
    const int swze = (((tid & 7) ^ (srow & 7)) << 3);
    int pix0 = Mbase + srow;
    int nn0 = pix0 >> 12, p0 = (pix0 >> 6) & 63, q0 = pix0 & 63;
    const int abase0 = nn0 * in_img + (STRIDE * p0) * in_row + (STRIDE * q0) * CIN + swze;
    const int astep = STRIDE * in_row;
    const int bbase0 = srow * CIN + swze;
    const int bstep = 64 * CIN;

    int colw[2];
#pragma unroll
    for (int kk = 0; kk < 2; ++kk)
        colw[kk] = (kk * 32 + (l >> 4) * 8) ^ ((l & 7) << 3);

    f32x4 acc[8][4] = {};
    bf16x8 afr[4][2], bXf[2][2], bYf[2][2];

#define AOFF(ks) (((NTAPS == 9) ? ((((ks) / CSTEPS) / 3) * in_row + (((ks) / CSTEPS) % 3) * CIN) : 0) + ((ks) % CSTEPS) * 64)
#define BOFF(ks) (((ks) / CSTEPS) * 256 * CIN + ((ks) % CSTEPS) * 64)
#define GLDS(gsrc, ldst) __builtin_amdgcn_global_load_lds(                          \
        (__attribute__((address_space(1))) void*)(gsrc),                            \
        (__attribute__((address_space(3))) void*)(ldst), 16, 0, 0)
#define STAGE_A(base, h, ks) {                                                      \
    int _ao = AOFF(ks);                                                             \
    GLDS(in + abase0 + (2 * (h) + 0) * astep + _ao,                                 \
         &lds[(base) + (h) * 8192 + 0 * 4096 + w * 512]);                           \
    GLDS(in + abase0 + (2 * (h) + 1) * astep + _ao,                                 \
         &lds[(base) + (h) * 8192 + 1 * 4096 + w * 512]); }
#define STAGE_B(base, h, ks) {                                                      \
    int _bo = BOFF(ks);                                                             \
    GLDS(wt + bbase0 + (2 * (h) + 0) * bstep + _bo,                                 \
         &lds[(base) + (h) * 8192 + 0 * 4096 + w * 512]);                           \
    GLDS(wt + bbase0 + (2 * (h) + 1) * bstep + _bo,                                 \
         &lds[(base) + (h) * 8192 + 1 * 4096 + w * 512]); }
#define BARRIER() { __builtin_amdgcn_s_barrier(); asm volatile("" ::: "memory"); }
#define LDA(base, MH) {                                                             \
    _Pragma("unroll") for (int fm = 0; fm < 4; ++fm)                                \
    _Pragma("unroll") for (int kk = 0; kk < 2; ++kk)                                \
        afr[fm][kk] = *(const bf16x8*)&lds[(base) + ((MH) * 128 + wm * 64 + fm * 16 + l15) * 64 + colw[kk]]; }
#define LDB(base, NH, dst) {                                                        \
    _Pragma("unroll") for (int gn = 0; gn < 2; ++gn)                                \
    _Pragma("unroll") for (int kk = 0; kk < 2; ++kk)                                \
        dst[gn][kk] = *(const bf16x8*)&lds[(base) + ((NH) * 128 + gn * 64 + wn * 16 + l15) * 64 + colw[kk]]; }
#define MFMA_Q(MH, NH, bset) {                                                      \
    _Pragma("unroll") for (int fm = 0; fm < 4; ++fm)                                \
    _Pragma("unroll") for (int gn = 0; gn < 2; ++gn)                                \
    _Pragma("unroll") for (int kk = 0; kk < 2; ++kk)                                \
        acc[(MH) * 4 + fm][(NH) * 2 + gn] = __builtin_amdgcn_mfma_f32_16x16x32_bf16( \
            afr[fm][kk], bset[gn][kk], acc[(MH) * 4 + fm][(NH) * 2 + gn], 0, 0, 0); }

    // ---- prologue: A(0),B(0),A(1); drain A(0)+B(0), keep A(1) flying ----
    STAGE_A(0, 0, 0); STAGE_A(0, 1, 0);
    STAGE_B(49152, 0, 0); STAGE_B(49152, 1, 0);
    STAGE_A(16384, 0, 1); STAGE_A(16384, 1, 1);
    asm volatile("s_waitcnt vmcnt(4)" ::: "memory");
    BARRIER();

    int Ar = 0;          // A read slot (tile t)
    int As = 32768;      // A stage slot (tile t+2)
    int Brel = 0;        // B read slot rel offset; stage = ^16384

    // ---- init: load B0(0) into bX (tile 0: b0-role = bX) ----
    LDB(49152, 0, bXf);

#define CBODY(T, B0, B1, STAGEA, VM)                                                \
    {                                                                               \
        const int Br = 49152 + Brel, Bs = 49152 + (Brel ^ 16384);                   \
        LDA(Ar, 0);                                                                 \
        LDB(Br, 1, B1);                                                             \
        STAGE_B(Bs, 0, (T) + 1); STAGE_B(Bs, 1, (T) + 1);                           \
        __builtin_amdgcn_s_setprio(1);                                              \
        MFMA_Q(0, 0, B0);                                                           \
        MFMA_Q(0, 1, B1);                                                           \
        __builtin_amdgcn_s_setprio(0);                                              \
        LDA(Ar, 1);                                                                 \
        if (STAGEA) { STAGE_A(As, 0, (T) + 2); STAGE_A(As, 1, (T) + 2); }           \
        __builtin_amdgcn_s_setprio(1);                                              \
        MFMA_Q(1, 1, B1);                                                           \
        __builtin_amdgcn_s_setprio(0);                                              \
        asm volatile("s_waitcnt vmcnt(" #VM ")" ::: "memory");                      \
        BARRIER();                                                                  \
        LDB(49152 + (Brel ^ 16384), 0, B1);  /* next tile's b0 -> dead set */       \
        __builtin_amdgcn_s_setprio(1);                                              \
        MFMA_Q(1, 0, B0);                    /* deferred, reg-only */               \
        __builtin_amdgcn_s_setprio(0);                                              \
        Ar = (Ar == 32768) ? 0 : Ar + 16384;                                        \
        As = (As == 32768) ? 0 : As + 16384;                                        \
        Brel ^= 16384;                                                              \
    }

    // ---- steady loop ----
#pragma unroll 1
    for (int t = 0; t < KT - 2; t += 2) {
        CBODY(t,     bXf, bYf, true, 4);
        CBODY(t + 1, bYf, bXf, true, 4);
    }

    // ---- tile KT-2 (b0=bX): stage only B(KT-1); drain everything ----
    CBODY(KT - 2, bXf, bYf, false, 0);

    // ---- tile KT-1 (b0=bY): fully resident ----
    {
        const int Br = 49152 + Brel;
        LDA(Ar, 0);
        LDB(Br, 1, bXf);
        MFMA_Q(0, 0, bYf);
        MFMA_Q(0, 1, bXf);
        LDA(Ar, 1);
        MFMA_Q(1, 1, bXf);
        MFMA_Q(1, 0, bYf);
    }
#undef CBODY
#undef AOFF
#undef BOFF
#undef GLDS
#undef STAGE_A
#undef STAGE_B
#undef LDA
#undef LDB

    // ---- epilogue: C frag (col=lane&15 -> o, row=(lane>>4)*4+j -> pixel) ----
#pragma unroll
    for (int f = 0; f < 8; ++f) {
        const int prow = (f >> 2) * 128 + wm * 64 + (f & 3) * 16 + ((l >> 4) << 2);
#pragma unroll
        for (int g = 0; g < 4; ++g) {
            const int o = (g >> 1) * 128 + (g & 1) * 64 + wn * 16 + l15;
            float bb = 0.f;
            if (BIASRELU) bb = bias[o];
#pragma unroll
            for (int j = 0; j < 4; ++j) {
                int pix = Mbase + prow + j;
                int nn = pix >> 12, p = (pix >> 6) & 63, q = pix & 63;
                float val = acc[f][g][j] + bb;
                if (BIASRELU) val = fmaxf(val, 0.f);
                out[out_base + nn * out_img + p * out_row + q * 256 + o] = f2bf(val);
            }
        }
    }

    // ---- fused SE pooling: per-block column sums (deterministic) ----
    if (POOL) {
        float ps[4];
#pragma unroll
        for (int g = 0; g < 4; ++g) {
            float s = 0.f;
#pragma unroll
            for (int f = 0; f < 8; ++f)
#pragma unroll
                for (int j = 0; j < 4; ++j) s += acc[f][g][j];
            s += __shfl_xor(s, 16);
            s += __shfl_xor(s, 32);
            ps[g] = s;
        }
        asm volatile("s_waitcnt lgkmcnt(0)" ::: "memory");
        BARRIER();
        float* fl = (float*)lds;
        if ((l >> 4) == 0) {
#pragma unroll
            for (int g = 0; g < 4; ++g) {
                int o = (g >> 1) * 128 + (g & 1) * 64 + wn * 16 + l15;
                fl[wm * 256 + o] = ps[g];
            }
        }
        BARRIER();
        if (tid < 256)
            pool_out[bid * 256 + tid] = fl[tid] + fl[256 + tid];
    }
#undef MFMA_Q
#undef BARRIER
}

// ---------------------------------------------------------------------------
// finalize: per block (n,p):
//   (1) residual 1x1 s2 conv for its 64 pixels via MFMA (A=pre, B=wrt direct
//       from global; K=128) -> resf LDS
//   (2) recompute SE gate a[n][:] from conv2's pooled partials (deterministic)
//   (3) out[n][o][p][q] = h2[n][p][q][o]*a[o] + resf[q][o]  (NHWC->NCHW)
// ---------------------------------------------------------------------------
__global__ __launch_bounds__(256, 2)
void finalize_kernel(const u16* __restrict__ h2, const u16* __restrict__ pre,
                     const u16* __restrict__ wrt, const float* __restrict__ part,
                     const float* __restrict__ sw1, const float* __restrict__ sb1,
                     const float* __restrict__ sw2, const float* __restrict__ sb2,
                     float* __restrict__ out) {
    __shared__ u16 th[256 * 68];
    __shared__ u16 resf[64 * 256];
    __shared__ float al[256];
    __shared__ float hl[16];
    int n = blockIdx.x >> 6, p = blockIdx.x & 63;
    int t = threadIdx.x;
    const int w = t >> 6, l = t & 63;
    const int l15 = l & 15, lk = (l >> 4) << 3;

    // ---- (1) residual MFMA: M=64 px (all), N=64 o per wave, K=128 ----
    f32x4 racc[4][4] = {};
    {
        const u16* pbase = pre + ((n * 129 + 2 * p) * 129) * 128;
#pragma unroll
        for (int ks = 0; ks < 4; ++ks) {
            bf16x8 af[4], bf[4];
#pragma unroll
            for (int fm = 0; fm < 4; ++fm) {
                int q = fm * 16 + l15;
                af[fm] = *(const bf16x8*)(pbase + (2 * q) * 128 + ks * 32 + lk);
            }
#pragma unroll
            for (int fn = 0; fn < 4; ++fn) {
                int o = w * 64 + fn * 16 + l15;
                bf[fn] = *(const bf16x8*)(wrt + o * 128 + ks * 32 + lk);
            }
#pragma unroll
            for (int fm = 0; fm < 4; ++fm)
#pragma unroll
                for (int fn = 0; fn < 4; ++fn)
                    racc[fm][fn] = __builtin_amdgcn_mfma_f32_16x16x32_bf16(
                        af[fm], bf[fn], racc[fm][fn], 0, 0, 0);
        }
#pragma unroll
        for (int fm = 0; fm < 4; ++fm)
#pragma unroll
            for (int fn = 0; fn < 4; ++fn)
#pragma unroll
                for (int j = 0; j < 4; ++j)
                    resf[(fm * 16 + ((l >> 4) << 2) + j) * 256 + w * 64 + fn * 16 + l15] =
                        f2bf(racc[fm][fn][j]);
    }

    // ---- (2) SE gate for image n ----
    {
        float s = 0.f;
#pragma unroll
        for (int k = 0; k < 16; ++k) s += part[(n * 16 + k) * 256 + t];
        al[t] = s * (1.0f / 4096.0f);          // mean
    }
    __syncthreads();                            // resf + mean ready
    if (t < 16) {
        float d = sb1[t];
        for (int c = 0; c < 256; ++c) d += al[c] * sw1[t * 256 + c];
        hl[t] = fmaxf(d, 0.f);
    }
    __syncthreads();
    {
        float z = sb2[t];
#pragma unroll
        for (int j = 0; j < 16; ++j) z += hl[j] * sw2[t * 16 + j];
        float a_t = 1.0f / (1.0f + expf(-z));
        __syncthreads();                        // all mean-reads done
        al[t] = a_t;                            // overwrite with gate
    }
    __syncthreads();

    // ---- (3) combine + NHWC->NCHW transpose ----
    int o8 = (t & 31) << 3, qr = t >> 5;
    int pixbase = n * 4096 + p * 64;
#pragma unroll
    for (int qi = 0; qi < 8; ++qi) {
        int q = qi * 8 + qr;
        u16x8 hv = *(const u16x8*)(h2 + (pixbase + q) * 256 + o8);
        u16x8 rv = *(const u16x8*)(resf + q * 256 + o8);
#pragma unroll
        for (int k = 0; k < 8; ++k) {
            float vv = bf2f(hv[k]) * al[o8 + k] + bf2f(rv[k]);
            th[(o8 + k) * 68 + q] = f2bf(vv);
        }
    }
    __syncthreads();
    int q4 = (t & 15) << 2, ob = t >> 4;
#pragma unroll
    for (int oi = 0; oi < 16; ++oi) {
        int o = oi * 16 + ob;
        float4 vv;
        vv.x = bf2f(th[o * 68 + q4 + 0]);
        vv.y = bf2f(th[o * 68 + q4 + 1]);
        vv.z = bf2f(th[o * 68 + q4 + 2]);
        vv.w = bf2f(th[o * 68 + q4 + 3]);
        *(float4*)(out + ((n * 256 + o) * 64 + p) * 64 + q4) = vv;
    }
}

// ---------------------------------------------------------------------------
// workspace layout (bytes)
// ---------------------------------------------------------------------------
static const size_t OFF_PRE  = 0;                       // 68,161,536 (alive thru finalize)
static const size_t OFF_H1   = 68161536;                // 35,684,352
static const size_t OFF_H2   = 103845888;               // 33,554,432
static const size_t OFF_W1T  = 137400320;               // 589,824
static const size_t OFF_W2T  = 137990144;               // 1,179,648
static const size_t OFF_WRT  = 139169792;               // 65,536
static const size_t OFF_B2F  = 139235328;               // 1,024
static const size_t OFF_PART = 139236352;               // 262,144 (256 tiles x 256 f32)

extern "C" void kernel_launch(void* const* d_in, const int* in_sizes, int n_in,
                              void* d_out, int out_size, void* d_ws, size_t ws_size,
                              hipStream_t stream) {
    (void)in_sizes; (void)n_in; (void)out_size; (void)ws_size;
    const float* x      = (const float*)d_in[0];
    const float* bn1_g  = (const float*)d_in[1];
    const float* bn1_b  = (const float*)d_in[2];
    const float* bn1_m  = (const float*)d_in[3];
    const float* bn1_v  = (const float*)d_in[4];
    const float* bn2_g  = (const float*)d_in[5];
    const float* bn2_b  = (const float*)d_in[6];
    const float* bn2_m  = (const float*)d_in[7];
    const float* bn2_v  = (const float*)d_in[8];
    const float* wc1    = (const float*)d_in[9];
    const float* wc2    = (const float*)d_in[10];
    const float* wres   = (const float*)d_in[11];
    const float* se_w1  = (const float*)d_in[12];
    const float* se_b1  = (const float*)d_in[13];
    const float* se_w2  = (const float*)d_in[14];
    const float* se_b2  = (const float*)d_in[15];

    char* ws = (char*)d_ws;
    u16*   pre    = (u16*)(ws + OFF_PRE);
    u16*   h1     = (u16*)(ws + OFF_H1);
    u16*   h2     = (u16*)(ws + OFF_H2);
    u16*   w1t    = (u16*)(ws + OFF_W1T);
    u16*   w2t    = (u16*)(ws + OFF_W2T);
    u16*   wrt    = (u16*)(ws + OFF_WRT);
    float* bias2f = (float*)(ws + OFF_B2F);
    float* part   = (float*)(ws + OFF_PART);
    float* out    = (float*)d_out;

    // setup: weights + pads + pre (one launch)
    setup_kernel<<<11849, 256, 0, stream>>>(x, bn1_g, bn1_b, bn1_m, bn1_v,
                                            wc1, wc2, wres, bn2_g, bn2_b, bn2_m, bn2_v,
                                            w1t, w2t, wrt, bias2f, pre, h1);

    // conv1: 3x3 s2, 128->256, +BN2(bias)+ReLU, out = padded h1 (base (1,1))
    conv_8ph<128, 9, 2, true, false><<<256, 512, 0, stream>>>(
        pre, w1t, bias2f, h1, nullptr,
        129 * 128, 129 * 129 * 128,
        67 * 256, 66 * 256, 66 * 66 * 256);

    // conv2: 3x3 s1, 256->256 + fused SE pooling (h2 in its own region now)
    conv_8ph<256, 9, 1, false, true><<<256, 512, 0, stream>>>(
        h1, w2t, nullptr, h2, part,
        66 * 256, 66 * 66 * 256,
        0, 64 * 256, 4096 * 256);

    // finalize: fused SE-MLP + residual 1x1 conv (from pre) + combine
    finalize_kernel<<<1024, 256, 0, stream>>>(h2, pre, wrt, part,
                                              se_w1, se_b1, se_w2, se_b2, out);
}

// Round 10
// 189.921 us; speedup vs baseline: 1.0465x; 1.0465x over previous
//
#include <hip/hip_runtime.h>

typedef unsigned short u16;
typedef __attribute__((ext_vector_type(8))) unsigned short u16x8;
typedef __attribute__((ext_vector_type(8))) __bf16 bf16x8;
typedef __attribute__((ext_vector_type(4))) float f32x4;

__device__ __forceinline__ float bf2f(u16 u) {
    return __uint_as_float(((unsigned)u) << 16);
}
__device__ __forceinline__ u16 f2bf(float f) {
    unsigned u = __float_as_uint(f);
    return (u16)((u + 0x7FFFu + ((u >> 16) & 1u)) >> 16);
}

// ---------------------------------------------------------------------------
// setup kernel: pre-transpose FIRST (long pole, starts at t=0), then weights,
// then pad zeroing.  LDS cut to ~18.5KB -> 8 blocks/CU (was 35KB -> 4).
//   [0,4096):      pre = relu(BN1(x)) NCHW f32 -> padded NHWC bf16; each block
//                  does a 64x-by-128c half-row (n = b>>8, y=(b&255)>>1,
//                  xh=(b&1)*64).  8 float4 loads/thread (coalesced 256B runs),
//                  XOR-swizzled tile cols (col = c ^ ((x>>2)<<3)), contiguous
//                  u16x8 read-back, coalesced 1KB/wave NHWC stores.
//   [4096,7681):   weight transform (w1t fused with BN2 scale, w2t, wrt, bias)
//   [7681,9737):   zero pre pad (y=128 row, x=128 col)
//   [9737,13897):  zero h1 pad
// ---------------------------------------------------------------------------
__global__ __launch_bounds__(256)
void setup_kernel(const float* __restrict__ x,
                  const float* __restrict__ g1, const float* __restrict__ b1,
                  const float* __restrict__ m1, const float* __restrict__ v1,
                  const float* __restrict__ w1, const float* __restrict__ w2,
                  const float* __restrict__ wr,
                  const float* __restrict__ g2, const float* __restrict__ b2,
                  const float* __restrict__ m2, const float* __restrict__ v2,
                  u16* __restrict__ w1t, u16* __restrict__ w2t,
                  u16* __restrict__ wrt, float* __restrict__ bias2f,
                  u16* __restrict__ pre, u16* __restrict__ h1) {
    __shared__ u16 tile[64 * 136];
    __shared__ float scf[128], bif[128];
    int b = blockIdx.x;
    int tid = threadIdx.x;
    if (b < 4096) {
        int n = b >> 8, rem = b & 255;
        int y = rem >> 1, xh = (rem & 1) << 6;
        if (tid < 128) {
            float sc = g1[tid] * rsqrtf(v1[tid] + 1e-5f);
            scf[tid] = sc;
            bif[tid] = b1[tid] - m1[tid] * sc;
        }
        __syncthreads();
        // read phase: 16-lane group reads 256B contiguous of one channel row
        const int lx = tid & 15;            // x-group lane
        const int cg = tid >> 4;            // channel offset 0..15
        const int x4 = lx << 2;             // local x base (0..60)
        const int sw = lx << 3;             // swizzle ((x>>2)&15)<<3
        const float* xb = x + (n << 21) + (y << 7) + xh + x4;
#pragma unroll
        for (int i = 0; i < 8; ++i) {
            int c = i * 16 + cg;
            float4 val = *(const float4*)(xb + (c << 14));
            float sc = scf[c], bi = bif[c];
            int col = c ^ sw;
            tile[(x4 + 0) * 136 + col] = f2bf(fmaxf(val.x * sc + bi, 0.f));
            tile[(x4 + 1) * 136 + col] = f2bf(fmaxf(val.y * sc + bi, 0.f));
            tile[(x4 + 2) * 136 + col] = f2bf(fmaxf(val.z * sc + bi, 0.f));
            tile[(x4 + 3) * 136 + col] = f2bf(fmaxf(val.w * sc + bi, 0.f));
        }
        __syncthreads();
        // write phase: contiguous u16x8 read-back (swizzle bits 3-6 only),
        // coalesced 1KB/wave NHWC stores
        int c0 = (tid & 15) << 3;
        int xo = tid >> 4;                  // 0..15
#pragma unroll
        for (int xi = 0; xi < 4; ++xi) {
            int xloc = xi * 16 + xo;
            int colb = c0 ^ ((xloc >> 2) << 3);
            u16x8 val = *(const u16x8*)&tile[xloc * 136 + colb];
            *(u16x8*)(pre + ((n * 129 + y) * 129 + xh + xloc) * 128 + c0) = val;
        }
    } else if (b < 4096 + 3585) {
        int i = (b - 4096) * 256 + tid;
        if (i < 294912) {
            int ci = i & 127; int t = i >> 7; int o = t & 255; int tap = t >> 8;
            int dy = tap / 3, dx = tap - dy * 3;
            float sc = g2[o] * rsqrtf(v2[o] + 1e-5f);
            w1t[i] = f2bf(w1[((o * 128 + ci) * 3 + dy) * 3 + dx] * sc);
        } else if (i < 294912 + 589824) {
            int j = i - 294912;
            int ci = j & 255; int t = j >> 8; int o = t & 255; int tap = t >> 8;
            int dy = tap / 3, dx = tap - dy * 3;
            w2t[j] = f2bf(w2[((o * 256 + ci) * 3 + dy) * 3 + dx]);
        } else if (i < 294912 + 589824 + 32768) {
            int j = i - (294912 + 589824);
            int ci = j & 127; int o = j >> 7;
            wrt[j] = f2bf(wr[o * 128 + ci]);
        } else {
            int o = i - (294912 + 589824 + 32768);
            if (o < 256) {
                float sc = g2[o] * rsqrtf(v2[o] + 1e-5f);
                bias2f[o] = b2[o] - m2[o] * sc;
            }
        }
    } else if (b < 4096 + 3585 + 2056) {
        int i = (b - (4096 + 3585)) * 256 + tid;
        if (i < 16 * 129 * 128) {
            int c = i & 127; int t = i >> 7; int n = t / 129; int xx = t - n * 129;
            pre[((n * 129 + 128) * 129 + xx) * 128 + c] = 0;
        } else {
            int j = i - 16 * 129 * 128;
            int c = j & 127; int t = j >> 7; int n = t >> 7; int y = t & 127;
            pre[((n * 129 + y) * 129 + 128) * 128 + c] = 0;
        }
    } else {
        int i = (b - (4096 + 3585 + 2056)) * 256 + tid;
        int c = i & 255;
        int t = i >> 8;
        int n = t / 260;
        int cl = t - n * 260;
        int y, x2;
        if (cl < 66)       { y = 0;  x2 = cl; }
        else if (cl < 132) { y = 65; x2 = cl - 66; }
        else if (cl < 196) { x2 = 0; y = cl - 131; }
        else               { x2 = 65; y = cl - 195; }
        h1[((n * 66 + y) * 66 + x2) * 256 + c] = 0;
    }
}

// ===========================================================================
// 256x256 implicit-GEMM conv.  A triple-buffered, B double-buffered.
// Deferred-quadrant software pipeline; one barrier + one counted vmcnt/tile.
// T1 XCD swizzle; T2 LDS swizzle via inverse-swizzled global source.
// POOL: conv2 fuses the SE global-avg partial sums into the epilogue.
// ===========================================================================
template <int CIN, int NTAPS, int STRIDE, bool BIASRELU, bool POOL>
__global__ __launch_bounds__(512, 2)
void conv_8ph(const u16* __restrict__ in, const u16* __restrict__ wt,
              const float* __restrict__ bias, u16* __restrict__ out,
              float* __restrict__ pool_out,
              int in_row, int in_img, int out_base, int out_row, int out_img) {
    constexpr int CSTEPS = CIN / 64;
    constexpr int KT = CSTEPS * NTAPS;
    // A buffers: 0, 16384, 32768 ; B buffers: 49152, 65536   (u16 units)
    __shared__ __attribute__((aligned(16))) u16 lds[81920];

    const int tid = threadIdx.x;
    const int w = tid >> 6, l = tid & 63;
    const int wm = w >> 2, wn = w & 3;
    const int l15 = l & 15;
    // T1: XCD-aware swizzle (bijective, 256 % 8 == 0)
    const int bid = ((blockIdx.x & 7) << 5) | (blockIdx.x >> 3);
    const int Mbase = bid << 8;

    const int srow = tid >> 3;
    const int swze = (((tid & 7) ^ (srow & 7)) << 3);
    int pix0 = Mbase + srow;
    int nn0 = pix0 >> 12, p0 = (pix0 >> 6) & 63, q0 = pix0 & 63;
    const int abase0 = nn0 * in_img + (STRIDE * p0) * in_row + (STRIDE * q0) * CIN + swze;
    const int astep = STRIDE * in_row;
    const int bbase0 = srow * CIN + swze;
    const int bstep = 64 * CIN;

    int colw[2];
#pragma unroll
    for (int kk = 0; kk < 2; ++kk)
        colw[kk] = (kk * 32 + (l >> 4) * 8) ^ ((l & 7) << 3);

    f32x4 acc[8][4] = {};
    bf16x8 afr[4][2], bXf[2][2], bYf[2][2];

#define AOFF(ks) (((NTAPS == 9) ? ((((ks) / CSTEPS) / 3) * in_row + (((ks) / CSTEPS) % 3) * CIN) : 0) + ((ks) % CSTEPS) * 64)
#define BOFF(ks) (((ks) / CSTEPS) * 256 * CIN + ((ks) % CSTEPS) * 64)
#define GLDS(gsrc, ldst) __builtin_amdgcn_global_load_lds(                          \
        (__attribute__((address_space(1))) void*)(gsrc),                            \
        (__attribute__((address_space(3))) void*)(ldst), 16, 0, 0)
#define STAGE_A(base, h, ks) {                                                      \
    int _ao = AOFF(ks);                                                             \
    GLDS(in + abase0 + (2 * (h) + 0) * astep + _ao,                                 \
         &lds[(base) + (h) * 8192 + 0 * 4096 + w * 512]);                           \
    GLDS(in + abase0 + (2 * (h) + 1) * astep + _ao,                                 \
         &lds[(base) + (h) * 8192 + 1 * 4096 + w * 512]); }
#define STAGE_B(base, h, ks) {                                                      \
    int _bo = BOFF(ks);                                                             \
    GLDS(wt + bbase0 + (2 * (h) + 0) * bstep + _bo,                                 \
         &lds[(base) + (h) * 8192 + 0 * 4096 + w * 512]);                           \
    GLDS(wt + bbase0 + (2 * (h) + 1) * bstep + _bo,                                 \
         &lds[(base) + (h) * 8192 + 1 * 4096 + w * 512]); }
#define BARRIER() { __builtin_amdgcn_s_barrier(); asm volatile("" ::: "memory"); }
#define LDA(base, MH) {                                                             \
    _Pragma("unroll") for (int fm = 0; fm < 4; ++fm)                                \
    _Pragma("unroll") for (int kk = 0; kk < 2; ++kk)                                \
        afr[fm][kk] = *(const bf16x8*)&lds[(base) + ((MH) * 128 + wm * 64 + fm * 16 + l15) * 64 + colw[kk]]; }
#define LDB(base, NH, dst) {                                                        \
    _Pragma("unroll") for (int gn = 0; gn < 2; ++gn)                                \
    _Pragma("unroll") for (int kk = 0; kk < 2; ++kk)                                \
        dst[gn][kk] = *(const bf16x8*)&lds[(base) + ((NH) * 128 + gn * 64 + wn * 16 + l15) * 64 + colw[kk]]; }
#define MFMA_Q(MH, NH, bset) {                                                      \
    _Pragma("unroll") for (int fm = 0; fm < 4; ++fm)                                \
    _Pragma("unroll") for (int gn = 0; gn < 2; ++gn)                                \
    _Pragma("unroll") for (int kk = 0; kk < 2; ++kk)                                \
        acc[(MH) * 4 + fm][(NH) * 2 + gn] = __builtin_amdgcn_mfma_f32_16x16x32_bf16( \
            afr[fm][kk], bset[gn][kk], acc[(MH) * 4 + fm][(NH) * 2 + gn], 0, 0, 0); }

    // ---- prologue: A(0),B(0),A(1); drain A(0)+B(0), keep A(1) flying ----
    STAGE_A(0, 0, 0); STAGE_A(0, 1, 0);
    STAGE_B(49152, 0, 0); STAGE_B(49152, 1, 0);
    STAGE_A(16384, 0, 1); STAGE_A(16384, 1, 1);
    asm volatile("s_waitcnt vmcnt(4)" ::: "memory");
    BARRIER();

    int Ar = 0;          // A read slot (tile t)
    int As = 32768;      // A stage slot (tile t+2)
    int Brel = 0;        // B read slot rel offset; stage = ^16384

    // ---- init: load B0(0) into bX (tile 0: b0-role = bX) ----
    LDB(49152, 0, bXf);

#define CBODY(T, B0, B1, STAGEA, VM)                                                \
    {                                                                               \
        const int Br = 49152 + Brel, Bs = 49152 + (Brel ^ 16384);                   \
        LDA(Ar, 0);                                                                 \
        LDB(Br, 1, B1);                                                             \
        STAGE_B(Bs, 0, (T) + 1); STAGE_B(Bs, 1, (T) + 1);                           \
        __builtin_amdgcn_s_setprio(1);                                              \
        MFMA_Q(0, 0, B0);                                                           \
        MFMA_Q(0, 1, B1);                                                           \
        __builtin_amdgcn_s_setprio(0);                                              \
        LDA(Ar, 1);                                                                 \
        if (STAGEA) { STAGE_A(As, 0, (T) + 2); STAGE_A(As, 1, (T) + 2); }           \
        __builtin_amdgcn_s_setprio(1);                                              \
        MFMA_Q(1, 1, B1);                                                           \
        __builtin_amdgcn_s_setprio(0);                                              \
        asm volatile("s_waitcnt vmcnt(" #VM ")" ::: "memory");                      \
        BARRIER();                                                                  \
        LDB(49152 + (Brel ^ 16384), 0, B1);  /* next tile's b0 -> dead set */       \
        __builtin_amdgcn_s_setprio(1);                                              \
        MFMA_Q(1, 0, B0);                    /* deferred, reg-only */               \
        __builtin_amdgcn_s_setprio(0);                                              \
        Ar = (Ar == 32768) ? 0 : Ar + 16384;                                        \
        As = (As == 32768) ? 0 : As + 16384;                                        \
        Brel ^= 16384;                                                              \
    }

    // ---- steady loop ----
#pragma unroll 1
    for (int t = 0; t < KT - 2; t += 2) {
        CBODY(t,     bXf, bYf, true, 4);
        CBODY(t + 1, bYf, bXf, true, 4);
    }

    // ---- tile KT-2 (b0=bX): stage only B(KT-1); drain everything ----
    CBODY(KT - 2, bXf, bYf, false, 0);

    // ---- tile KT-1 (b0=bY): fully resident ----
    {
        const int Br = 49152 + Brel;
        LDA(Ar, 0);
        LDB(Br, 1, bXf);
        MFMA_Q(0, 0, bYf);
        MFMA_Q(0, 1, bXf);
        LDA(Ar, 1);
        MFMA_Q(1, 1, bXf);
        MFMA_Q(1, 0, bYf);
    }
#undef CBODY
#undef AOFF
#undef BOFF
#undef GLDS
#undef STAGE_A
#undef STAGE_B
#undef LDA
#undef LDB

    // ---- epilogue: C frag (col=lane&15 -> o, row=(lane>>4)*4+j -> pixel) ----
#pragma unroll
    for (int f = 0; f < 8; ++f) {
        const int prow = (f >> 2) * 128 + wm * 64 + (f & 3) * 16 + ((l >> 4) << 2);
#pragma unroll
        for (int g = 0; g < 4; ++g) {
            const int o = (g >> 1) * 128 + (g & 1) * 64 + wn * 16 + l15;
            float bb = 0.f;
            if (BIASRELU) bb = bias[o];
#pragma unroll
            for (int j = 0; j < 4; ++j) {
                int pix = Mbase + prow + j;
                int nn = pix >> 12, p = (pix >> 6) & 63, q = pix & 63;
                float val = acc[f][g][j] + bb;
                if (BIASRELU) val = fmaxf(val, 0.f);
                out[out_base + nn * out_img + p * out_row + q * 256 + o] = f2bf(val);
            }
        }
    }

    // ---- fused SE pooling: per-block column sums (deterministic) ----
    if (POOL) {
        float ps[4];
#pragma unroll
        for (int g = 0; g < 4; ++g) {
            float s = 0.f;
#pragma unroll
            for (int f = 0; f < 8; ++f)
#pragma unroll
                for (int j = 0; j < 4; ++j) s += acc[f][g][j];
            s += __shfl_xor(s, 16);
            s += __shfl_xor(s, 32);
            ps[g] = s;
        }
        asm volatile("s_waitcnt lgkmcnt(0)" ::: "memory");
        BARRIER();
        float* fl = (float*)lds;
        if ((l >> 4) == 0) {
#pragma unroll
            for (int g = 0; g < 4; ++g) {
                int o = (g >> 1) * 128 + (g & 1) * 64 + wn * 16 + l15;
                fl[wm * 256 + o] = ps[g];
            }
        }
        BARRIER();
        if (tid < 256)
            pool_out[bid * 256 + tid] = fl[tid] + fl[256 + tid];
    }
#undef MFMA_Q
#undef BARRIER
}

// ---------------------------------------------------------------------------
// finalize: per block (n,p):
//   (1) residual 1x1 s2 conv for its 64 pixels via MFMA (A=pre, B=wrt direct
//       from global; K=128) -> resf LDS
//   (2) recompute SE gate a[n][:] from conv2's pooled partials (deterministic)
//   (3) out[n][o][p][q] = h2[n][p][q][o]*a[o] + resf[q][o]  (NHWC->NCHW)
// ---------------------------------------------------------------------------
__global__ __launch_bounds__(256, 2)
void finalize_kernel(const u16* __restrict__ h2, const u16* __restrict__ pre,
                     const u16* __restrict__ wrt, const float* __restrict__ part,
                     const float* __restrict__ sw1, const float* __restrict__ sb1,
                     const float* __restrict__ sw2, const float* __restrict__ sb2,
                     float* __restrict__ out) {
    __shared__ u16 th[256 * 68];
    __shared__ u16 resf[64 * 256];
    __shared__ float al[256];
    __shared__ float hl[16];
    int n = blockIdx.x >> 6, p = blockIdx.x & 63;
    int t = threadIdx.x;
    const int w = t >> 6, l = t & 63;
    const int l15 = l & 15, lk = (l >> 4) << 3;

    // ---- (1) residual MFMA: M=64 px (all), N=64 o per wave, K=128 ----
    f32x4 racc[4][4] = {};
    {
        const u16* pbase = pre + ((n * 129 + 2 * p) * 129) * 128;
#pragma unroll
        for (int ks = 0; ks < 4; ++ks) {
            bf16x8 af[4], bf[4];
#pragma unroll
            for (int fm = 0; fm < 4; ++fm) {
                int q = fm * 16 + l15;
                af[fm] = *(const bf16x8*)(pbase + (2 * q) * 128 + ks * 32 + lk);
            }
#pragma unroll
            for (int fn = 0; fn < 4; ++fn) {
                int o = w * 64 + fn * 16 + l15;
                bf[fn] = *(const bf16x8*)(wrt + o * 128 + ks * 32 + lk);
            }
#pragma unroll
            for (int fm = 0; fm < 4; ++fm)
#pragma unroll
                for (int fn = 0; fn < 4; ++fn)
                    racc[fm][fn] = __builtin_amdgcn_mfma_f32_16x16x32_bf16(
                        af[fm], bf[fn], racc[fm][fn], 0, 0, 0);
        }
#pragma unroll
        for (int fm = 0; fm < 4; ++fm)
#pragma unroll
            for (int fn = 0; fn < 4; ++fn)
#pragma unroll
                for (int j = 0; j < 4; ++j)
                    resf[(fm * 16 + ((l >> 4) << 2) + j) * 256 + w * 64 + fn * 16 + l15] =
                        f2bf(racc[fm][fn][j]);
    }

    // ---- (2) SE gate for image n ----
    {
        float s = 0.f;
#pragma unroll
        for (int k = 0; k < 16; ++k) s += part[(n * 16 + k) * 256 + t];
        al[t] = s * (1.0f / 4096.0f);          // mean
    }
    __syncthreads();                            // resf + mean ready
    if (t < 16) {
        float d = sb1[t];
        for (int c = 0; c < 256; ++c) d += al[c] * sw1[t * 256 + c];
        hl[t] = fmaxf(d, 0.f);
    }
    __syncthreads();
    {
        float z = sb2[t];
#pragma unroll
        for (int j = 0; j < 16; ++j) z += hl[j] * sw2[t * 16 + j];
        float a_t = 1.0f / (1.0f + expf(-z));
        __syncthreads();                        // all mean-reads done
        al[t] = a_t;                            // overwrite with gate
    }
    __syncthreads();

    // ---- (3) combine + NHWC->NCHW transpose ----
    int o8 = (t & 31) << 3, qr = t >> 5;
    int pixbase = n * 4096 + p * 64;
#pragma unroll
    for (int qi = 0; qi < 8; ++qi) {
        int q = qi * 8 + qr;
        u16x8 hv = *(const u16x8*)(h2 + (pixbase + q) * 256 + o8);
        u16x8 rv = *(const u16x8*)(resf + q * 256 + o8);
#pragma unroll
        for (int k = 0; k < 8; ++k) {
            float vv = bf2f(hv[k]) * al[o8 + k] + bf2f(rv[k]);
            th[(o8 + k) * 68 + q] = f2bf(vv);
        }
    }
    __syncthreads();
    int q4 = (t & 15) << 2, ob = t >> 4;
#pragma unroll
    for (int oi = 0; oi < 16; ++oi) {
        int o = oi * 16 + ob;
        float4 vv;
        vv.x = bf2f(th[o * 68 + q4 + 0]);
        vv.y = bf2f(th[o * 68 + q4 + 1]);
        vv.z = bf2f(th[o * 68 + q4 + 2]);
        vv.w = bf2f(th[o * 68 + q4 + 3]);
        *(float4*)(out + ((n * 256 + o) * 64 + p) * 64 + q4) = vv;
    }
}

// ---------------------------------------------------------------------------
// workspace layout (bytes)
// ---------------------------------------------------------------------------
static const size_t OFF_PRE  = 0;                       // 68,161,536 (alive thru finalize)
static const size_t OFF_H1   = 68161536;                // 35,684,352
static const size_t OFF_H2   = 103845888;               // 33,554,432
static const size_t OFF_W1T  = 137400320;               // 589,824
static const size_t OFF_W2T  = 137990144;               // 1,179,648
static const size_t OFF_WRT  = 139169792;               // 65,536
static const size_t OFF_B2F  = 139235328;               // 1,024
static const size_t OFF_PART = 139236352;               // 262,144 (256 tiles x 256 f32)

extern "C" void kernel_launch(void* const* d_in, const int* in_sizes, int n_in,
                              void* d_out, int out_size, void* d_ws, size_t ws_size,
                              hipStream_t stream) {
    (void)in_sizes; (void)n_in; (void)out_size; (void)ws_size;
    const float* x      = (const float*)d_in[0];
    const float* bn1_g  = (const float*)d_in[1];
    const float* bn1_b  = (const float*)d_in[2];
    const float* bn1_m  = (const float*)d_in[3];
    const float* bn1_v  = (const float*)d_in[4];
    const float* bn2_g  = (const float*)d_in[5];
    const float* bn2_b  = (const float*)d_in[6];
    const float* bn2_m  = (const float*)d_in[7];
    const float* bn2_v  = (const float*)d_in[8];
    const float* wc1    = (const float*)d_in[9];
    const float* wc2    = (const float*)d_in[10];
    const float* wres   = (const float*)d_in[11];
    const float* se_w1  = (const float*)d_in[12];
    const float* se_b1  = (const float*)d_in[13];
    const float* se_w2  = (const float*)d_in[14];
    const float* se_b2  = (const float*)d_in[15];

    char* ws = (char*)d_ws;
    u16*   pre    = (u16*)(ws + OFF_PRE);
    u16*   h1     = (u16*)(ws + OFF_H1);
    u16*   h2     = (u16*)(ws + OFF_H2);
    u16*   w1t    = (u16*)(ws + OFF_W1T);
    u16*   w2t    = (u16*)(ws + OFF_W2T);
    u16*   wrt    = (u16*)(ws + OFF_WRT);
    float* bias2f = (float*)(ws + OFF_B2F);
    float* part   = (float*)(ws + OFF_PART);
    float* out    = (float*)d_out;

    // setup: pre-transpose first, then weights + pads (one launch)
    setup_kernel<<<13897, 256, 0, stream>>>(x, bn1_g, bn1_b, bn1_m, bn1_v,
                                            wc1, wc2, wres, bn2_g, bn2_b, bn2_m, bn2_v,
                                            w1t, w2t, wrt, bias2f, pre, h1);

    // conv1: 3x3 s2, 128->256, +BN2(bias)+ReLU, out = padded h1 (base (1,1))
    conv_8ph<128, 9, 2, true, false><<<256, 512, 0, stream>>>(
        pre, w1t, bias2f, h1, nullptr,
        129 * 128, 129 * 129 * 128,
        67 * 256, 66 * 256, 66 * 66 * 256);

    // conv2: 3x3 s1, 256->256 + fused SE pooling (h2 in its own region now)
    conv_8ph<256, 9, 1, false, true><<<256, 512, 0, stream>>>(
        h1, w2t, nullptr, h2, part,
        66 * 256, 66 * 66 * 256,
        0, 64 * 256, 4096 * 256);

    // finalize: fused SE-MLP + residual 1x1 conv (from pre) + combine
    finalize_kernel<<<1024, 256, 0, stream>>>(h2, pre, wrt, part,
                                              se_w1, se_b1, se_w2, se_b2, out);
}

// Round 11
// 189.264 us; speedup vs baseline: 1.0501x; 1.0035x over previous
//
#include <hip/hip_runtime.h>

typedef unsigned short u16;
typedef __attribute__((ext_vector_type(8))) unsigned short u16x8;
typedef __attribute__((ext_vector_type(8))) __bf16 bf16x8;
typedef __attribute__((ext_vector_type(4))) float f32x4;

__device__ __forceinline__ float bf2f(u16 u) {
    return __uint_as_float(((unsigned)u) << 16);
}
__device__ __forceinline__ u16 f2bf(float f) {
    unsigned u = __float_as_uint(f);
    return (u16)((u + 0x7FFFu + ((u >> 16) & 1u)) >> 16);
}

// ---------------------------------------------------------------------------
// setup kernel: pre-transpose FIRST (long pole), then weights, then pads.
//   [0,4096):      pre = relu(BN1(x)) NCHW f32 -> padded NHWC bf16.
//                  T14 split: all 8 float4 loads issued FIRST (independent,
//                  in-flight together), BN-param setup + barrier overlap the
//                  load latency, then convert + swizzled LDS stores, then
//                  contiguous u16x8 readback + coalesced NHWC stores.
//   [4096,7681):   weight transform; [7681,9737): pre pad; [9737,13897): h1 pad
// ---------------------------------------------------------------------------
__global__ __launch_bounds__(256)
void setup_kernel(const float* __restrict__ x,
                  const float* __restrict__ g1, const float* __restrict__ b1,
                  const float* __restrict__ m1, const float* __restrict__ v1,
                  const float* __restrict__ w1, const float* __restrict__ w2,
                  const float* __restrict__ wr,
                  const float* __restrict__ g2, const float* __restrict__ b2,
                  const float* __restrict__ m2, const float* __restrict__ v2,
                  u16* __restrict__ w1t, u16* __restrict__ w2t,
                  u16* __restrict__ wrt, float* __restrict__ bias2f,
                  u16* __restrict__ pre, u16* __restrict__ h1) {
    __shared__ u16 tile[64 * 136];
    __shared__ float scf[128], bif[128];
    int b = blockIdx.x;
    int tid = threadIdx.x;
    if (b < 4096) {
        int n = b >> 8, rem = b & 255;
        int y = rem >> 1, xh = (rem & 1) << 6;
        const int lx = tid & 15;            // x-group lane
        const int cg = tid >> 4;            // channel offset 0..15
        const int x4 = lx << 2;             // local x base (0..60)
        const int sw = lx << 3;             // swizzle ((x>>2)&15)<<3
        const float* xb = x + (n << 21) + (y << 7) + xh + x4;
        // ---- T14 phase 1: issue ALL loads (independent; fill the MC queue)
        float4 v0 = *(const float4*)(xb + ((0 * 16 + cg) << 14));
        float4 v1r = *(const float4*)(xb + ((1 * 16 + cg) << 14));
        float4 v2r = *(const float4*)(xb + ((2 * 16 + cg) << 14));
        float4 v3 = *(const float4*)(xb + ((3 * 16 + cg) << 14));
        float4 v4 = *(const float4*)(xb + ((4 * 16 + cg) << 14));
        float4 v5 = *(const float4*)(xb + ((5 * 16 + cg) << 14));
        float4 v6 = *(const float4*)(xb + ((6 * 16 + cg) << 14));
        float4 v7 = *(const float4*)(xb + ((7 * 16 + cg) << 14));
        // ---- param setup + barrier overlap the loads
        if (tid < 128) {
            float sc = g1[tid] * rsqrtf(v1[tid] + 1e-5f);
            scf[tid] = sc;
            bif[tid] = b1[tid] - m1[tid] * sc;
        }
        __syncthreads();
        // ---- T14 phase 2: convert + swizzled LDS stores
#define PUT(I, V) {                                                        \
        int c = (I) * 16 + cg;                                             \
        float sc = scf[c], bi = bif[c];                                    \
        int col = c ^ sw;                                                  \
        tile[(x4 + 0) * 136 + col] = f2bf(fmaxf((V).x * sc + bi, 0.f));    \
        tile[(x4 + 1) * 136 + col] = f2bf(fmaxf((V).y * sc + bi, 0.f));    \
        tile[(x4 + 2) * 136 + col] = f2bf(fmaxf((V).z * sc + bi, 0.f));    \
        tile[(x4 + 3) * 136 + col] = f2bf(fmaxf((V).w * sc + bi, 0.f)); }
        PUT(0, v0) PUT(1, v1r) PUT(2, v2r) PUT(3, v3)
        PUT(4, v4) PUT(5, v5) PUT(6, v6) PUT(7, v7)
#undef PUT
        __syncthreads();
        // ---- readback: contiguous u16x8 (swizzle bits 3-6 only), coalesced
        int c0 = (tid & 15) << 3;
        int xo = tid >> 4;                  // 0..15
#pragma unroll
        for (int xi = 0; xi < 4; ++xi) {
            int xloc = xi * 16 + xo;
            int colb = c0 ^ ((xloc >> 2) << 3);
            u16x8 val = *(const u16x8*)&tile[xloc * 136 + colb];
            *(u16x8*)(pre + ((n * 129 + y) * 129 + xh + xloc) * 128 + c0) = val;
        }
    } else if (b < 4096 + 3585) {
        int i = (b - 4096) * 256 + tid;
        if (i < 294912) {
            int ci = i & 127; int t = i >> 7; int o = t & 255; int tap = t >> 8;
            int dy = tap / 3, dx = tap - dy * 3;
            float sc = g2[o] * rsqrtf(v2[o] + 1e-5f);
            w1t[i] = f2bf(w1[((o * 128 + ci) * 3 + dy) * 3 + dx] * sc);
        } else if (i < 294912 + 589824) {
            int j = i - 294912;
            int ci = j & 255; int t = j >> 8; int o = t & 255; int tap = t >> 8;
            int dy = tap / 3, dx = tap - dy * 3;
            w2t[j] = f2bf(w2[((o * 256 + ci) * 3 + dy) * 3 + dx]);
        } else if (i < 294912 + 589824 + 32768) {
            int j = i - (294912 + 589824);
            int ci = j & 127; int o = j >> 7;
            wrt[j] = f2bf(wr[o * 128 + ci]);
        } else {
            int o = i - (294912 + 589824 + 32768);
            if (o < 256) {
                float sc = g2[o] * rsqrtf(v2[o] + 1e-5f);
                bias2f[o] = b2[o] - m2[o] * sc;
            }
        }
    } else if (b < 4096 + 3585 + 2056) {
        int i = (b - (4096 + 3585)) * 256 + tid;
        if (i < 16 * 129 * 128) {
            int c = i & 127; int t = i >> 7; int n = t / 129; int xx = t - n * 129;
            pre[((n * 129 + 128) * 129 + xx) * 128 + c] = 0;
        } else {
            int j = i - 16 * 129 * 128;
            int c = j & 127; int t = j >> 7; int n = t >> 7; int y = t & 127;
            pre[((n * 129 + y) * 129 + 128) * 128 + c] = 0;
        }
    } else {
        int i = (b - (4096 + 3585 + 2056)) * 256 + tid;
        int c = i & 255;
        int t = i >> 8;
        int n = t / 260;
        int cl = t - n * 260;
        int y, x2;
        if (cl < 66)       { y = 0;  x2 = cl; }
        else if (cl < 132) { y = 65; x2 = cl - 66; }
        else if (cl < 196) { x2 = 0; y = cl - 131; }
        else               { x2 = 65; y = cl - 195; }
        h1[((n * 66 + y) * 66 + x2) * 256 + c] = 0;
    }
}

// ===========================================================================
// 256x256 implicit-GEMM conv.  A triple-buffered, B double-buffered.
// Deferred-quadrant software pipeline; one barrier + one counted vmcnt/tile.
// T1 XCD swizzle; T2 LDS swizzle via inverse-swizzled global source.
// POOL: conv2 fuses the SE global-avg partial sums into the epilogue.
// ===========================================================================
template <int CIN, int NTAPS, int STRIDE, bool BIASRELU, bool POOL>
__global__ __launch_bounds__(512, 2)
void conv_8ph(const u16* __restrict__ in, const u16* __restrict__ wt,
              const float* __restrict__ bias, u16* __restrict__ out,
              float* __restrict__ pool_out,
              int in_row, int in_img, int out_base, int out_row, int out_img) {
    constexpr int CSTEPS = CIN / 64;
    constexpr int KT = CSTEPS * NTAPS;
    // A buffers: 0, 16384, 32768 ; B buffers: 49152, 65536   (u16 units)
    __shared__ __attribute__((aligned(16))) u16 lds[81920];

    const int tid = threadIdx.x;
    const int w = tid >> 6, l = tid & 63;
    const int wm = w >> 2, wn = w & 3;
    const int l15 = l & 15;
    // T1: XCD-aware swizzle (bijective, 256 % 8 == 0)
    const int bid = ((blockIdx.x & 7) << 5) | (blockIdx.x >> 3);
    const int Mbase = bid << 8;

    const int srow = tid >> 3;
    const int swze = (((tid & 7) ^ (srow & 7)) << 3);
    int pix0 = Mbase + srow;
    int nn0 = pix0 >> 12, p0 = (pix0 >> 6) & 63, q0 = pix0 & 63;
    const int abase0 = nn0 * in_img + (STRIDE * p0) * in_row + (STRIDE * q0) * CIN + swze;
    const int astep = STRIDE * in_row;
    const int bbase0 = srow * CIN + swze;
    const int bstep = 64 * CIN;

    int colw[2];
#pragma unroll
    for (int kk = 0; kk < 2; ++kk)
        colw[kk] = (kk * 32 + (l >> 4) * 8) ^ ((l & 7) << 3);

    f32x4 acc[8][4] = {};
    bf16x8 afr[4][2], bXf[2][2], bYf[2][2];

#define AOFF(ks) (((NTAPS == 9) ? ((((ks) / CSTEPS) / 3) * in_row + (((ks) / CSTEPS) % 3) * CIN) : 0) + ((ks) % CSTEPS) * 64)
#define BOFF(ks) (((ks) / CSTEPS) * 256 * CIN + ((ks) % CSTEPS) * 64)
#define GLDS(gsrc, ldst) __builtin_amdgcn_global_load_lds(                          \
        (__attribute__((address_space(1))) void*)(gsrc),                            \
        (__attribute__((address_space(3))) void*)(ldst), 16, 0, 0)
#define STAGE_A(base, h, ks) {                                                      \
    int _ao = AOFF(ks);                                                             \
    GLDS(in + abase0 + (2 * (h) + 0) * astep + _ao,                                 \
         &lds[(base) + (h) * 8192 + 0 * 4096 + w * 512]);                           \
    GLDS(in + abase0 + (2 * (h) + 1) * astep + _ao,                                 \
         &lds[(base) + (h) * 8192 + 1 * 4096 + w * 512]); }
#define STAGE_B(base, h, ks) {                                                      \
    int _bo = BOFF(ks);                                                             \
    GLDS(wt + bbase0 + (2 * (h) + 0) * bstep + _bo,                                 \
         &lds[(base) + (h) * 8192 + 0 * 4096 + w * 512]);                           \
    GLDS(wt + bbase0 + (2 * (h) + 1) * bstep + _bo,                                 \
         &lds[(base) + (h) * 8192 + 1 * 4096 + w * 512]); }
#define BARRIER() { __builtin_amdgcn_s_barrier(); asm volatile("" ::: "memory"); }
#define LDA(base, MH) {                                                             \
    _Pragma("unroll") for (int fm = 0; fm < 4; ++fm)                                \
    _Pragma("unroll") for (int kk = 0; kk < 2; ++kk)                                \
        afr[fm][kk] = *(const bf16x8*)&lds[(base) + ((MH) * 128 + wm * 64 + fm * 16 + l15) * 64 + colw[kk]]; }
#define LDB(base, NH, dst) {                                                        \
    _Pragma("unroll") for (int gn = 0; gn < 2; ++gn)                                \
    _Pragma("unroll") for (int kk = 0; kk < 2; ++kk)                                \
        dst[gn][kk] = *(const bf16x8*)&lds[(base) + ((NH) * 128 + gn * 64 + wn * 16 + l15) * 64 + colw[kk]]; }
#define MFMA_Q(MH, NH, bset) {                                                      \
    _Pragma("unroll") for (int fm = 0; fm < 4; ++fm)                                \
    _Pragma("unroll") for (int gn = 0; gn < 2; ++gn)                                \
    _Pragma("unroll") for (int kk = 0; kk < 2; ++kk)                                \
        acc[(MH) * 4 + fm][(NH) * 2 + gn] = __builtin_amdgcn_mfma_f32_16x16x32_bf16( \
            afr[fm][kk], bset[gn][kk], acc[(MH) * 4 + fm][(NH) * 2 + gn], 0, 0, 0); }

    // ---- prologue: A(0),B(0),A(1); drain A(0)+B(0), keep A(1) flying ----
    STAGE_A(0, 0, 0); STAGE_A(0, 1, 0);
    STAGE_B(49152, 0, 0); STAGE_B(49152, 1, 0);
    STAGE_A(16384, 0, 1); STAGE_A(16384, 1, 1);
    asm volatile("s_waitcnt vmcnt(4)" ::: "memory");
    BARRIER();

    int Ar = 0;          // A read slot (tile t)
    int As = 32768;      // A stage slot (tile t+2)
    int Brel = 0;        // B read slot rel offset; stage = ^16384

    // ---- init: load B0(0) into bX (tile 0: b0-role = bX) ----
    LDB(49152, 0, bXf);

#define CBODY(T, B0, B1, STAGEA, VM)                                                \
    {                                                                               \
        const int Br = 49152 + Brel, Bs = 49152 + (Brel ^ 16384);                   \
        LDA(Ar, 0);                                                                 \
        LDB(Br, 1, B1);                                                             \
        STAGE_B(Bs, 0, (T) + 1); STAGE_B(Bs, 1, (T) + 1);                           \
        __builtin_amdgcn_s_setprio(1);                                              \
        MFMA_Q(0, 0, B0);                                                           \
        MFMA_Q(0, 1, B1);                                                           \
        __builtin_amdgcn_s_setprio(0);                                              \
        LDA(Ar, 1);                                                                 \
        if (STAGEA) { STAGE_A(As, 0, (T) + 2); STAGE_A(As, 1, (T) + 2); }           \
        __builtin_amdgcn_s_setprio(1);                                              \
        MFMA_Q(1, 1, B1);                                                           \
        __builtin_amdgcn_s_setprio(0);                                              \
        asm volatile("s_waitcnt vmcnt(" #VM ")" ::: "memory");                      \
        BARRIER();                                                                  \
        LDB(49152 + (Brel ^ 16384), 0, B1);  /* next tile's b0 -> dead set */       \
        __builtin_amdgcn_s_setprio(1);                                              \
        MFMA_Q(1, 0, B0);                    /* deferred, reg-only */               \
        __builtin_amdgcn_s_setprio(0);                                              \
        Ar = (Ar == 32768) ? 0 : Ar + 16384;                                        \
        As = (As == 32768) ? 0 : As + 16384;                                        \
        Brel ^= 16384;                                                              \
    }

    // ---- steady loop ----
#pragma unroll 1
    for (int t = 0; t < KT - 2; t += 2) {
        CBODY(t,     bXf, bYf, true, 4);
        CBODY(t + 1, bYf, bXf, true, 4);
    }

    // ---- tile KT-2 (b0=bX): stage only B(KT-1); drain everything ----
    CBODY(KT - 2, bXf, bYf, false, 0);

    // ---- tile KT-1 (b0=bY): fully resident ----
    {
        const int Br = 49152 + Brel;
        LDA(Ar, 0);
        LDB(Br, 1, bXf);
        MFMA_Q(0, 0, bYf);
        MFMA_Q(0, 1, bXf);
        LDA(Ar, 1);
        MFMA_Q(1, 1, bXf);
        MFMA_Q(1, 0, bYf);
    }
#undef CBODY
#undef AOFF
#undef BOFF
#undef GLDS
#undef STAGE_A
#undef STAGE_B
#undef LDA
#undef LDB

    // ---- epilogue: C frag (col=lane&15 -> o, row=(lane>>4)*4+j -> pixel) ----
#pragma unroll
    for (int f = 0; f < 8; ++f) {
        const int prow = (f >> 2) * 128 + wm * 64 + (f & 3) * 16 + ((l >> 4) << 2);
#pragma unroll
        for (int g = 0; g < 4; ++g) {
            const int o = (g >> 1) * 128 + (g & 1) * 64 + wn * 16 + l15;
            float bb = 0.f;
            if (BIASRELU) bb = bias[o];
#pragma unroll
            for (int j = 0; j < 4; ++j) {
                int pix = Mbase + prow + j;
                int nn = pix >> 12, p = (pix >> 6) & 63, q = pix & 63;
                float val = acc[f][g][j] + bb;
                if (BIASRELU) val = fmaxf(val, 0.f);
                out[out_base + nn * out_img + p * out_row + q * 256 + o] = f2bf(val);
            }
        }
    }

    // ---- fused SE pooling: per-block column sums (deterministic) ----
    if (POOL) {
        float ps[4];
#pragma unroll
        for (int g = 0; g < 4; ++g) {
            float s = 0.f;
#pragma unroll
            for (int f = 0; f < 8; ++f)
#pragma unroll
                for (int j = 0; j < 4; ++j) s += acc[f][g][j];
            s += __shfl_xor(s, 16);
            s += __shfl_xor(s, 32);
            ps[g] = s;
        }
        asm volatile("s_waitcnt lgkmcnt(0)" ::: "memory");
        BARRIER();
        float* fl = (float*)lds;
        if ((l >> 4) == 0) {
#pragma unroll
            for (int g = 0; g < 4; ++g) {
                int o = (g >> 1) * 128 + (g & 1) * 64 + wn * 16 + l15;
                fl[wm * 256 + o] = ps[g];
            }
        }
        BARRIER();
        if (tid < 256)
            pool_out[bid * 256 + tid] = fl[tid] + fl[256 + tid];
    }
#undef MFMA_Q
#undef BARRIER
}

// ---------------------------------------------------------------------------
// finalize: per block (n,p):
//   (1) residual 1x1 s2 conv for its 64 pixels via MFMA (A=pre, B=wrt direct
//       from global; K=128) -> resf LDS
//   (2) recompute SE gate a[n][:] from conv2's pooled partials (deterministic)
//   (3) out[n][o][p][q] = h2[n][p][q][o]*a[o] + resf[q][o]  (NHWC->NCHW)
// ---------------------------------------------------------------------------
__global__ __launch_bounds__(256, 2)
void finalize_kernel(const u16* __restrict__ h2, const u16* __restrict__ pre,
                     const u16* __restrict__ wrt, const float* __restrict__ part,
                     const float* __restrict__ sw1, const float* __restrict__ sb1,
                     const float* __restrict__ sw2, const float* __restrict__ sb2,
                     float* __restrict__ out) {
    __shared__ u16 th[256 * 68];
    __shared__ u16 resf[64 * 256];
    __shared__ float al[256];
    __shared__ float hl[16];
    int n = blockIdx.x >> 6, p = blockIdx.x & 63;
    int t = threadIdx.x;
    const int w = t >> 6, l = t & 63;
    const int l15 = l & 15, lk = (l >> 4) << 3;

    // ---- (1) residual MFMA: M=64 px (all), N=64 o per wave, K=128 ----
    f32x4 racc[4][4] = {};
    {
        const u16* pbase = pre + ((n * 129 + 2 * p) * 129) * 128;
#pragma unroll
        for (int ks = 0; ks < 4; ++ks) {
            bf16x8 af[4], bf[4];
#pragma unroll
            for (int fm = 0; fm < 4; ++fm) {
                int q = fm * 16 + l15;
                af[fm] = *(const bf16x8*)(pbase + (2 * q) * 128 + ks * 32 + lk);
            }
#pragma unroll
            for (int fn = 0; fn < 4; ++fn) {
                int o = w * 64 + fn * 16 + l15;
                bf[fn] = *(const bf16x8*)(wrt + o * 128 + ks * 32 + lk);
            }
#pragma unroll
            for (int fm = 0; fm < 4; ++fm)
#pragma unroll
                for (int fn = 0; fn < 4; ++fn)
                    racc[fm][fn] = __builtin_amdgcn_mfma_f32_16x16x32_bf16(
                        af[fm], bf[fn], racc[fm][fn], 0, 0, 0);
        }
#pragma unroll
        for (int fm = 0; fm < 4; ++fm)
#pragma unroll
            for (int fn = 0; fn < 4; ++fn)
#pragma unroll
                for (int j = 0; j < 4; ++j)
                    resf[(fm * 16 + ((l >> 4) << 2) + j) * 256 + w * 64 + fn * 16 + l15] =
                        f2bf(racc[fm][fn][j]);
    }

    // ---- (2) SE gate for image n ----
    {
        float s = 0.f;
#pragma unroll
        for (int k = 0; k < 16; ++k) s += part[(n * 16 + k) * 256 + t];
        al[t] = s * (1.0f / 4096.0f);          // mean
    }
    __syncthreads();                            // resf + mean ready
    if (t < 16) {
        float d = sb1[t];
        for (int c = 0; c < 256; ++c) d += al[c] * sw1[t * 256 + c];
        hl[t] = fmaxf(d, 0.f);
    }
    __syncthreads();
    {
        float z = sb2[t];
#pragma unroll
        for (int j = 0; j < 16; ++j) z += hl[j] * sw2[t * 16 + j];
        float a_t = 1.0f / (1.0f + expf(-z));
        __syncthreads();                        // all mean-reads done
        al[t] = a_t;                            // overwrite with gate
    }
    __syncthreads();

    // ---- (3) combine + NHWC->NCHW transpose ----
    int o8 = (t & 31) << 3, qr = t >> 5;
    int pixbase = n * 4096 + p * 64;
#pragma unroll
    for (int qi = 0; qi < 8; ++qi) {
        int q = qi * 8 + qr;
        u16x8 hv = *(const u16x8*)(h2 + (pixbase + q) * 256 + o8);
        u16x8 rv = *(const u16x8*)(resf + q * 256 + o8);
#pragma unroll
        for (int k = 0; k < 8; ++k) {
            float vv = bf2f(hv[k]) * al[o8 + k] + bf2f(rv[k]);
            th[(o8 + k) * 68 + q] = f2bf(vv);
        }
    }
    __syncthreads();
    int q4 = (t & 15) << 2, ob = t >> 4;
#pragma unroll
    for (int oi = 0; oi < 16; ++oi) {
        int o = oi * 16 + ob;
        float4 vv;
        vv.x = bf2f(th[o * 68 + q4 + 0]);
        vv.y = bf2f(th[o * 68 + q4 + 1]);
        vv.z = bf2f(th[o * 68 + q4 + 2]);
        vv.w = bf2f(th[o * 68 + q4 + 3]);
        *(float4*)(out + ((n * 256 + o) * 64 + p) * 64 + q4) = vv;
    }
}

// ---------------------------------------------------------------------------
// workspace layout (bytes)
// ---------------------------------------------------------------------------
static const size_t OFF_PRE  = 0;                       // 68,161,536 (alive thru finalize)
static const size_t OFF_H1   = 68161536;                // 35,684,352
static const size_t OFF_H2   = 103845888;               // 33,554,432
static const size_t OFF_W1T  = 137400320;               // 589,824
static const size_t OFF_W2T  = 137990144;               // 1,179,648
static const size_t OFF_WRT  = 139169792;               // 65,536
static const size_t OFF_B2F  = 139235328;               // 1,024
static const size_t OFF_PART = 139236352;               // 262,144 (256 tiles x 256 f32)

extern "C" void kernel_launch(void* const* d_in, const int* in_sizes, int n_in,
                              void* d_out, int out_size, void* d_ws, size_t ws_size,
                              hipStream_t stream) {
    (void)in_sizes; (void)n_in; (void)out_size; (void)ws_size;
    const float* x      = (const float*)d_in[0];
    const float* bn1_g  = (const float*)d_in[1];
    const float* bn1_b  = (const float*)d_in[2];
    const float* bn1_m  = (const float*)d_in[3];
    const float* bn1_v  = (const float*)d_in[4];
    const float* bn2_g  = (const float*)d_in[5];
    const float* bn2_b  = (const float*)d_in[6];
    const float* bn2_m  = (const float*)d_in[7];
    const float* bn2_v  = (const float*)d_in[8];
    const float* wc1    = (const float*)d_in[9];
    const float* wc2    = (const float*)d_in[10];
    const float* wres   = (const float*)d_in[11];
    const float* se_w1  = (const float*)d_in[12];
    const float* se_b1  = (const float*)d_in[13];
    const float* se_w2  = (const float*)d_in[14];
    const float* se_b2  = (const float*)d_in[15];

    char* ws = (char*)d_ws;
    u16*   pre    = (u16*)(ws + OFF_PRE);
    u16*   h1     = (u16*)(ws + OFF_H1);
    u16*   h2     = (u16*)(ws + OFF_H2);
    u16*   w1t    = (u16*)(ws + OFF_W1T);
    u16*   w2t    = (u16*)(ws + OFF_W2T);
    u16*   wrt    = (u16*)(ws + OFF_WRT);
    float* bias2f = (float*)(ws + OFF_B2F);
    float* part   = (float*)(ws + OFF_PART);
    float* out    = (float*)d_out;

    // setup: pre-transpose first, then weights + pads (one launch)
    setup_kernel<<<13897, 256, 0, stream>>>(x, bn1_g, bn1_b, bn1_m, bn1_v,
                                            wc1, wc2, wres, bn2_g, bn2_b, bn2_m, bn2_v,
                                            w1t, w2t, wrt, bias2f, pre, h1);

    // conv1: 3x3 s2, 128->256, +BN2(bias)+ReLU, out = padded h1 (base (1,1))
    conv_8ph<128, 9, 2, true, false><<<256, 512, 0, stream>>>(
        pre, w1t, bias2f, h1, nullptr,
        129 * 128, 129 * 129 * 128,
        67 * 256, 66 * 256, 66 * 66 * 256);

    // conv2: 3x3 s1, 256->256 + fused SE pooling (h2 in its own region now)
    conv_8ph<256, 9, 1, false, true><<<256, 512, 0, stream>>>(
        h1, w2t, nullptr, h2, part,
        66 * 256, 66 * 66 * 256,
        0, 64 * 256, 4096 * 256);

    // finalize: fused SE-MLP + residual 1x1 conv (from pre) + combine
    finalize_kernel<<<1024, 256, 0, stream>>>(h2, pre, wrt, part,
                                              se_w1, se_b1, se_w2, se_b2, out);
}